// Round 3
// baseline (124.262 us; speedup 1.0000x reference)
//
#include <hip/hip_runtime.h>
#include <math.h>

#define B_DIM 1024
#define D_DIM 512
#define H_DIM 128
#define S_DIM 511
#define PI_F 3.14159265358979323846f
#define ZSWZ_BYTES (8u * 1024u * 128u)      /* 1 MiB: z bf16, swizzle-baked */
#define NTILES_TOTAL 2296                    /* sum over s of ceil((s+1)/64) */
#define W1BF_BYTES ((size_t)NTILES_TOTAL * 16384)

typedef __attribute__((ext_vector_type(8))) short short8;
typedef __attribute__((ext_vector_type(4))) float f32x4;

static __device__ __forceinline__ unsigned cvt_pk_bf16(float lo, float hi) {
    unsigned r;
    asm("v_cvt_pk_bf16_f32 %0, %1, %2" : "=v"(r) : "v"(lo), "v"(hi));
    return r;
}

// tiles before site s in the triangular-packed W1bf buffer
static __device__ __host__ __forceinline__ int tiles_before(int s) {
    const int q = s >> 6, r = s & 63;
    return s + 32 * q * (q - 1) + q * r;
}

// ---------------------------------------------------------------------------
// Pack kernel. Blocks [0,256): z f32 -> bf16 swizzled tiles (A operand).
// Blocks [256,...): W1 f32 [k][h] -> bf16 [h][k] swizzled tiles (B operand),
// triangular-packed, mask (k>s -> 0) baked in.
// Global B-tile layout: byte h*128 + c holds bf16 of W1[s][k0 + ((c^((h&7)<<4))>>1)][h].
// ---------------------------------------------------------------------------
__global__ __launch_bounds__(256) void pack_kernel(
        const float* __restrict__ z, const float* __restrict__ W1,
        unsigned char* __restrict__ z_swz, unsigned char* __restrict__ w1bf)
{
    if (blockIdx.x < 256) {
        const int gid = blockIdx.x * 256 + threadIdx.x;   // 65536 threads
        const int g   = gid & 7;
        const int row = (gid >> 3) & 1023;
        const int kt  = gid >> 13;
        const int srcg = g ^ (row & 7);
        const float* src = z + (size_t)row * D_DIM + kt * 64 + srcg * 8;
        float4 a = *(const float4*)src;
        float4 b = *(const float4*)(src + 4);
        uint4 w;
        w.x = cvt_pk_bf16(a.x, a.y);
        w.y = cvt_pk_bf16(a.z, a.w);
        w.z = cvt_pk_bf16(b.x, b.y);
        w.w = cvt_pk_bf16(b.z, b.w);
        *(uint4*)(z_swz + (size_t)kt * 131072 + row * 128 + g * 16) = w;
        return;
    }
    const int tb = blockIdx.x - 256;          // 0..4087
    const int s  = tb >> 3;
    const int kk = tb & 7;
    if (s >= S_DIM || kk > (s >> 6)) return;  // kk < ntiles(s) = (s>>6)+1
    const int k0 = kk << 6;
    const int t  = threadIdx.x;
    const int h  = t >> 1;                    // 0..127
    const int khalf = t & 1;                  // owns m = khalf*4 .. +3
    const float* __restrict__ W1s = W1 + (size_t)s * (D_DIM * H_DIM) + h;
    unsigned char* out = w1bf + (size_t)(tiles_before(s) + kk) * 16384 + h * 128;
    const int sw = (h & 7);
#pragma unroll
    for (int mm = 0; mm < 4; ++mm) {
        const int m = khalf * 4 + mm;
        float v[8];
#pragma unroll
        for (int e = 0; e < 8; ++e) {
            const int gk = k0 + m * 8 + e;
            v[e] = (gk <= s) ? W1s[(size_t)gk * H_DIM] : 0.f;
        }
        uint4 w;
        w.x = cvt_pk_bf16(v[0], v[1]);
        w.y = cvt_pk_bf16(v[2], v[3]);
        w.z = cvt_pk_bf16(v[4], v[5]);
        w.w = cvt_pk_bf16(v[6], v[7]);
        *(uint4*)(out + ((m ^ sw) << 4)) = w;
    }
}

// ---------------------------------------------------------------------------
// Main site kernel. PRE=true: both operands staged via global_load_lds from
// pre-packed bf16 (z_swz / w1bf). PRE=false: legacy in-kernel conversion.
// ---------------------------------------------------------------------------
template<bool PRE>
__global__ __launch_bounds__(256) void ar_site_kernel(
        const float* __restrict__ z, const unsigned char* __restrict__ z_swz,
        const unsigned char* __restrict__ w1bf,
        const float* __restrict__ W1, const float* __restrict__ b1,
        const float* __restrict__ W2, const float* __restrict__ b2,
        float* __restrict__ x_out, float* __restrict__ ld_part,
        float* __restrict__ ld_out)
{
    __shared__ __align__(16) unsigned char lds[32768];  // A:[0,16K) Bt:[16K,32K); reused for p-partials

    // XCD grouping: 8 b-blocks of one site share blockIdx%8 -> same XCD L2.
    const int ib    = blockIdx.x;
    const int s_idx = ((ib >> 6) << 3) | (ib & 7);
    if (s_idx >= S_DIM) return;
    const int s     = S_DIM - 1 - s_idx;                // descending K
    const int bblk  = (ib >> 3) & 7;
    const int brow0 = bblk * 128;
    const int K     = s + 1;
    const int idx   = s + 1;
    const int tid   = threadIdx.x;
    const int lane  = tid & 63;
    const int wid   = tid >> 6;
    const int wr    = wid >> 1;
    const int wc    = wid & 1;
    const int l15   = lane & 15;
    const int l16   = lane >> 4;

    const float* __restrict__ W1s = W1 + (size_t)s * (D_DIM * H_DIM);
    const unsigned char* __restrict__ w1tile =
        PRE ? (w1bf + (size_t)tiles_before(s) * 16384) : nullptr;

    f32x4 acc[4][4];
#pragma unroll
    for (int mi = 0; mi < 4; ++mi)
#pragma unroll
        for (int ni = 0; ni < 4; ++ni)
            acc[mi][ni] = (f32x4){0.f, 0.f, 0.f, 0.f};

    const int ntiles = (K + 63) >> 6;
    for (int kk = 0; kk < ntiles; ++kk) {
        const int k0 = kk << 6;

        if (PRE) {
            // ---- stage A: z bf16 swizzled tiles
            const unsigned char* srcA = z_swz + (size_t)kk * 131072 + (size_t)brow0 * 128
                                        + wid * 4096 + lane * 16;
            unsigned char* dstA = lds + wid * 4096;
            // ---- stage B: pre-packed W1 bf16 tile
            const unsigned char* srcB = w1tile + (size_t)kk * 16384 + wid * 4096 + lane * 16;
            unsigned char* dstB = lds + 16384 + wid * 4096;
#pragma unroll
            for (int i2 = 0; i2 < 4; ++i2) {
                __builtin_amdgcn_global_load_lds(
                    (const __attribute__((address_space(1))) unsigned int*)(srcA + i2 * 1024),
                    (__attribute__((address_space(3))) unsigned int*)(dstA + i2 * 1024),
                    16, 0, 0);
                __builtin_amdgcn_global_load_lds(
                    (const __attribute__((address_space(1))) unsigned int*)(srcB + i2 * 1024),
                    (__attribute__((address_space(3))) unsigned int*)(dstB + i2 * 1024),
                    16, 0, 0);
            }
        } else {
            // legacy: convert z in-kernel
            const int g  = tid & 7;
            const int rb = tid >> 3;
#pragma unroll
            for (int p = 0; p < 4; ++p) {
                const int row  = p * 32 + rb;
                const int srcg = g ^ (row & 7);
                const float* zp = z + (size_t)(brow0 + row) * D_DIM + k0 + srcg * 8;
                float4 va = *(const float4*)zp;
                float4 vb = *(const float4*)(zp + 4);
                uint4 w;
                w.x = cvt_pk_bf16(va.x, va.y);
                w.y = cvt_pk_bf16(va.z, va.w);
                w.z = cvt_pk_bf16(vb.x, vb.y);
                w.w = cvt_pk_bf16(vb.z, vb.w);
                *(uint4*)(lds + row * 128 + g * 16) = w;
            }
            // legacy: convert W1 in-kernel
            const int hgrp  = tid & 31;
            const int kgrp  = tid >> 5;
            const int kbase = k0 + kgrp * 8;
            const float* wp = W1s + (size_t)kbase * H_DIM + hgrp * 4;
            float4 c[8];
#pragma unroll
            for (int j = 0; j < 8; ++j) {
                float4 v = *(const float4*)(wp + (size_t)j * H_DIM);
                const bool ok = (kbase + j) < K;
                v.x = ok ? v.x : 0.f;  v.y = ok ? v.y : 0.f;
                v.z = ok ? v.z : 0.f;  v.w = ok ? v.w : 0.f;
                c[j] = v;
            }
            const float* cf = (const float*)c;
#pragma unroll
            for (int i2 = 0; i2 < 4; ++i2) {
                const int h = hgrp * 4 + i2;
                uint4 w;
                w.x = cvt_pk_bf16(cf[0 * 4 + i2], cf[1 * 4 + i2]);
                w.y = cvt_pk_bf16(cf[2 * 4 + i2], cf[3 * 4 + i2]);
                w.z = cvt_pk_bf16(cf[4 * 4 + i2], cf[5 * 4 + i2]);
                w.w = cvt_pk_bf16(cf[6 * 4 + i2], cf[7 * 4 + i2]);
                *(uint4*)(lds + 16384 + h * 128 + ((kgrp * 16) ^ ((h & 7) << 4))) = w;
            }
        }

        __syncthreads();   // drains vmcnt (global_load_lds) + lgkmcnt

        // ---- MFMA: 2 k-steps of 32
#pragma unroll
        for (int ks = 0; ks < 2; ++ks) {
            const int kb = ks * 64 + l16 * 16;
            short8 af[4], bfr[4];
#pragma unroll
            for (int mi = 0; mi < 4; ++mi) {
                const int r = wr * 64 + mi * 16 + l15;
                af[mi] = *(const short8*)(lds + r * 128 + (kb ^ ((r & 7) << 4)));
            }
#pragma unroll
            for (int ni = 0; ni < 4; ++ni) {
                const int h = wc * 64 + ni * 16 + l15;
                bfr[ni] = *(const short8*)(lds + 16384 + h * 128 + (kb ^ ((h & 7) << 4)));
            }
#pragma unroll
            for (int mi = 0; mi < 4; ++mi)
#pragma unroll
                for (int ni = 0; ni < 4; ++ni)
                    acc[mi][ni] = __builtin_amdgcn_mfma_f32_16x16x32_bf16(
                        af[mi], bfr[ni], acc[mi][ni], 0, 0, 0);
        }
        __syncthreads();
    }

    // ---- epilogue: h = relu(acc + b1); per-lane partials of p = h @ W2
    float b1v[4], w2a[4], w2b[4];
#pragma unroll
    for (int ni = 0; ni < 4; ++ni) {
        const int c = wc * 64 + ni * 16 + l15;
        b1v[ni] = b1[(size_t)s * H_DIM + c];
        const float* w2p = W2 + ((size_t)s * H_DIM + c) * 2;
        w2a[ni] = w2p[0];
        w2b[ni] = w2p[1];
    }
#pragma unroll
    for (int mi = 0; mi < 4; ++mi) {
#pragma unroll
        for (int r = 0; r < 4; ++r) {
            float p0 = 0.f, p1 = 0.f;
#pragma unroll
            for (int ni = 0; ni < 4; ++ni) {
                float h = acc[mi][ni][r] + b1v[ni];
                h = fmaxf(h, 0.f);
                p0 = fmaf(h, w2a[ni], p0);
                p1 = fmaf(h, w2b[ni], p1);
            }
            const int row = wr * 64 + mi * 16 + l16 * 4 + r;
            const int sw  = (row & 15) << 4;
            *(float*)(lds + row * 256 + ((wc * 128 + l15 * 4) ^ sw))      = p0;
            *(float*)(lds + row * 256 + ((wc * 128 + 64 + l15 * 4) ^ sw)) = p1;
        }
    }
    __syncthreads();

    // ---- reduce partials, NCP transform, write x column + ld partial
    if (tid < 128) {
        const int row = tid;
        const int sw  = (row & 15) << 4;
        float asum = 0.f, bsum = 0.f;
#pragma unroll
        for (int wcb = 0; wcb < 2; ++wcb) {
#pragma unroll
            for (int q = 0; q < 4; ++q) {
                f32x4 va = *(const f32x4*)(lds + row * 256 + ((wcb * 128 + q * 16) ^ sw));
                f32x4 vb = *(const f32x4*)(lds + row * 256 + ((wcb * 128 + 64 + q * 16) ^ sw));
                asum += va.x + va.y + va.z + va.w;
                bsum += vb.x + vb.y + vb.z + vb.w;
            }
        }
        const int grow = brow0 + row;
        const float alpha = asum + b2[(size_t)s * 2 + 0];
        const float beta  = bsum + b2[(size_t)s * 2 + 1];
        const float phi = z[(size_t)grow * D_DIM + idx];
        const float u = tanf(0.5f * (phi - PI_F));
        const float a = expf(alpha);
        const float v = fmaf(a, u, beta);
        x_out[(size_t)grow * D_DIM + idx] = 2.0f * atanf(v) + PI_F;
        const float ld = alpha + log1pf(u * u) - log1pf(v * v);
        if (PRE) ld_part[(size_t)s * B_DIM + grow] = ld;
        else     atomicAdd(ld_out + grow, ld);
    }
}

__global__ __launch_bounds__(256) void ar_finalize(
        const float* __restrict__ z, const float* __restrict__ ld_part,
        float* __restrict__ x_out, float* __restrict__ ld_out, int use_ws)
{
    const int b = blockIdx.x * blockDim.x + threadIdx.x;
    if (b >= B_DIM) return;
    x_out[(size_t)b * D_DIM] = z[(size_t)b * D_DIM];   // untouched column 0
    if (use_ws) {
        float acc = 0.f;
        for (int i = 0; i < S_DIM; ++i)
            acc += ld_part[(size_t)i * B_DIM + b];
        ld_out[b] = acc;
    }
}

extern "C" void kernel_launch(void* const* d_in, const int* in_sizes, int n_in,
                              void* d_out, int out_size, void* d_ws, size_t ws_size,
                              hipStream_t stream) {
    const float* z  = (const float*)d_in[0];
    const float* W1 = (const float*)d_in[1];
    const float* b1 = (const float*)d_in[2];
    const float* W2 = (const float*)d_in[3];
    const float* b2 = (const float*)d_in[4];
    float* x_out  = (float*)d_out;
    float* ld_out = x_out + (size_t)B_DIM * D_DIM;

    unsigned char* z_swz = (unsigned char*)d_ws;
    unsigned char* w1bf  = z_swz + ZSWZ_BYTES;
    float* ld_part = (float*)(w1bf + W1BF_BYTES);
    const size_t need = ZSWZ_BYTES + W1BF_BYTES + (size_t)S_DIM * B_DIM * sizeof(float);

    if (ws_size >= need) {
        pack_kernel<<<dim3(256 + 4088), dim3(256), 0, stream>>>(z, W1, z_swz, w1bf);
        ar_site_kernel<true><<<dim3(4096), dim3(256), 0, stream>>>(
            z, z_swz, w1bf, W1, b1, W2, b2, x_out, ld_part, ld_out);
        ar_finalize<<<dim3(4), dim3(256), 0, stream>>>(z, ld_part, x_out, ld_out, 1);
    } else {
        hipMemsetAsync(ld_out, 0, B_DIM * sizeof(float), stream);
        ar_site_kernel<false><<<dim3(4096), dim3(256), 0, stream>>>(
            z, nullptr, nullptr, W1, b1, W2, b2, x_out, nullptr, ld_out);
        ar_finalize<<<dim3(4), dim3(256), 0, stream>>>(z, nullptr, x_out, ld_out, 0);
    }
}